// Round 8
// baseline (389.391 us; speedup 1.0000x reference)
//
#include <hip/hip_runtime.h>
#include <math.h>

#define BB 64
#define DD 512
#define MM 8192
#define TPB2 512   // k2 threads: 8 waves
#define CPT2 16    // MM / TPB2 cold columns per thread

typedef unsigned long long u64;

// ---------------- DPP wave-64 primitives ----------------
template<int CTRL>
__device__ __forceinline__ float dpp_addf(float x) {
    int y = __builtin_amdgcn_update_dpp(0, __float_as_int(x), CTRL, 0xF, 0xF, true);
    return x + __int_as_float(y);
}
__device__ __forceinline__ float wave_sum64(float x) {
    x = dpp_addf<0x111>(x); x = dpp_addf<0x112>(x); x = dpp_addf<0x114>(x); x = dpp_addf<0x118>(x);
    x = dpp_addf<0x142>(x); x = dpp_addf<0x143>(x);
    return __int_as_float(__builtin_amdgcn_readlane(__float_as_int(x), 63));
}
template<int CTRL>
__device__ __forceinline__ u64 dpp_min_step(u64 k) {
    unsigned lo = (unsigned)k, hi = (unsigned)(k >> 32);
    unsigned nlo = (unsigned)__builtin_amdgcn_update_dpp((int)0xFFFFFFFFu, (int)lo, CTRL, 0xF, 0xF, false);
    unsigned nhi = (unsigned)__builtin_amdgcn_update_dpp((int)0xFFFFFFFFu, (int)hi, CTRL, 0xF, 0xF, false);
    u64 nk = (((u64)nhi) << 32) | (u64)nlo;
    return nk < k ? nk : k;
}
__device__ __forceinline__ u64 wave_min64(u64 k) {
    k = dpp_min_step<0x111>(k); k = dpp_min_step<0x112>(k); k = dpp_min_step<0x114>(k);
    k = dpp_min_step<0x118>(k); k = dpp_min_step<0x142>(k); k = dpp_min_step<0x143>(k);
    unsigned lo = (unsigned)__builtin_amdgcn_readlane((int)(unsigned)k, 63);
    unsigned hi = (unsigned)__builtin_amdgcn_readlane((int)(unsigned)(k >> 32), 63);
    return (((u64)hi) << 32) | (u64)lo;
}

// ---------------- K01: blocks 0..255 = k1 (S0p, n2p); block 256 = k0 (G, Pfx) ----------------
// k0 body: 256-thread remake with IDENTICAL per-element accumulation order as R7's k0
// (chunks d0 ascending, dl ascending; same shuffle tree per Pfx row) -> bit-identical G/Pfx.
__global__ __launch_bounds__(256) void k01(const float* __restrict__ K, const float* __restrict__ MK0,
                                           float* __restrict__ S0p, float* __restrict__ n2p,
                                           float* __restrict__ G, float* __restrict__ Pfx) {
    __shared__ float lds[12352];           // k0: Ks 64*129 + Gs 64*64 ; k1: Ks 4160 + Ms 4160 + sq 256
    const int tid = threadIdx.x;
    const int lane = tid & 63, w = tid >> 6;

    if (blockIdx.x == 256) {
        // ---------------- k0 ----------------
        float* Ks = lds;                   // [64][129]
        float* Gs = lds + 64 * 129;        // [64][64]
        const int s = lane;
        const int rq = w;                  // 4 quads x 16 rows
        float acc[16];
        #pragma unroll
        for (int i = 0; i < 16; ++i) acc[i] = 0.f;
        for (int d0 = 0; d0 < DD; d0 += 128) {
            #pragma unroll
            for (int i = 0; i < 32; ++i) {
                int e = i * 256 + tid; int r = e >> 7, c = e & 127;
                Ks[r * 129 + c] = K[r * DD + d0 + c];
            }
            __syncthreads();
            for (int dl = 0; dl < 128; ++dl) {
                float kv = Ks[s * 129 + dl];
                #pragma unroll
                for (int i = 0; i < 16; ++i) acc[i] += Ks[(rq * 16 + i) * 129 + dl] * kv;
            }
            __syncthreads();
        }
        #pragma unroll
        for (int i = 0; i < 16; ++i) {
            G[(rq * 16 + i) * BB + s] = acc[i];
            Gs[(rq * 16 + i) * BB + s] = acc[i];
        }
        __syncthreads();
        #pragma unroll 1
        for (int r = 0; r < 16; ++r) {
            int row = rq * 16 + r;
            float x = (s < row) ? Gs[row * BB + s] : 0.f;
            #pragma unroll
            for (int o = 1; o < 64; o <<= 1) {
                float y = __shfl_down(x, o);
                if (s + o < 64) x += y;
            }
            Pfx[row * BB + s] = x;
        }
        return;
    }

    // ---------------- k1 (verbatim R7 arithmetic) ----------------
    float* Ks = lds;                       // [64*65]
    float* Ms = lds + 4160;                // [64*65]
    float* sq = lds + 8320;                // [256]
    const int bx = blockIdx.x;
    const int jb = (bx & 127) * 64;
    const int dbase = (bx >> 7) * 256;
    const int t4 = ((w << 2) | (lane >> 4)) << 2;
    const int jq0 = lane & 15;
    float acc[4][4];
    #pragma unroll
    for (int i = 0; i < 4; ++i)
        #pragma unroll
        for (int q = 0; q < 4; ++q) acc[i][q] = 0.f;
    float sqa = 0.f;
    for (int dt = 0; dt < 4; ++dt) {
        int d0 = dbase + dt * 64;
        #pragma unroll
        for (int i = 0; i < 16; ++i) {
            int e = i * 256 + tid; int r = e >> 6, c = e & 63;
            Ks[r * 65 + c] = K[r * DD + d0 + c];
            float m = MK0[(d0 + r) * MM + jb + c];
            Ms[r * 65 + c] = m;
            sqa += m * m;
        }
        __syncthreads();
        #pragma unroll 4
        for (int dl = 0; dl < 64; ++dl) {
            float kv[4], mv[4];
            #pragma unroll
            for (int i = 0; i < 4; ++i) kv[i] = Ks[(t4 + i) * 65 + dl];
            #pragma unroll
            for (int q = 0; q < 4; ++q) mv[q] = Ms[dl * 65 + jq0 + 16 * q];
            #pragma unroll
            for (int i = 0; i < 4; ++i)
                #pragma unroll
                for (int q = 0; q < 4; ++q) acc[i][q] += kv[i] * mv[q];
        }
        __syncthreads();
    }
    #pragma unroll
    for (int i = 0; i < 4; ++i)
        #pragma unroll
        for (int q = 0; q < 4; ++q)
            S0p[(bx >> 7) * BB * MM + (t4 + i) * MM + jb + jq0 + 16 * q] = acc[i][q];
    sq[w * 64 + lane] = sqa;
    __syncthreads();
    if (w == 0) n2p[(bx >> 7) * MM + jb + lane] =
        sq[lane] + sq[64 + lane] + sq[128 + lane] + sq[192 + lane];
}

// ---------------- K1b: cold-hypothesis E matrix ----------------
__global__ __launch_bounds__(256) void k1b_ecold(const float* __restrict__ S0p,
                                                 const float* __restrict__ G,
                                                 const float* __restrict__ Pfx,
                                                 const float* __restrict__ n2p,
                                                 const float* __restrict__ bp,
                                                 float* __restrict__ Ecold) {
    __shared__ float Pfx0s[BB], invks[BB], k2s[BB];
    int tid = threadIdx.x;
    int j = blockIdx.x * 256 + tid;
    if (tid < BB) {
        float g = G[tid * BB + tid];
        k2s[tid] = g;
        invks[tid] = __builtin_amdgcn_rsqf(g);
        Pfx0s[tid] = Pfx[tid * BB + 0];
    }
    const float beta = 1.f / (1.f + expf(-bp[0]));
    const float cuni = beta / (float)MM;
    float n2c = n2p[j] + n2p[MM + j];
    __syncthreads();
    for (int t = 0; t < BB; ++t) {
        float s0 = S0p[t * MM + j] + S0p[(BB + t) * MM + j];
        float d_ = s0 + cuni * Pfx0s[t];
        float cosv = d_ * invks[t] * __builtin_amdgcn_rsqf(n2c);
        float ee = __expf(cosv);
        Ecold[t * MM + j] = ee;
        n2c = n2c + 2.f * cuni * d_ + cuni * cuni * k2s[t];
    }
}

// ---------------- KS: Scold[t] = sum_j Ecold[t][j] ----------------
__global__ __launch_bounds__(256) void ks_rowsum(const float* __restrict__ Ecold, float* __restrict__ Scold) {
    __shared__ float sw[4];
    int t = blockIdx.x, tid = threadIdx.x;
    int lane = tid & 63, wid = tid >> 6;
    float s = 0.f;
    #pragma unroll
    for (int i = 0; i < 32; ++i) s += Ecold[t * MM + i * 256 + tid];
    #pragma unroll
    for (int o = 32; o > 0; o >>= 1) s += __shfl_down(s, o);
    if (lane == 0) sw[wid] = s;
    __syncthreads();
    if (tid == 0) Scold[t] = sw[0] + sw[1] + sw[2] + sw[3];
}

// ---------------- K2: 64-step scan; 8 waves, 16 cols/thread, DPP reductions, 1 barrier/step ----------------
// Arithmetic bit-identical to R7: same per-column fma order, same DPP trees, exact (value,index)
// min (associative -> regrouping 16->8 partials preserves the result), G/Pfx/Scold via LDS (same bits).
__global__ __launch_bounds__(512) void k2_scan(const float* __restrict__ Ecold,
                                               const float* __restrict__ G,
                                               const float* __restrict__ Pfx,
                                               const float* __restrict__ Scoldg,
                                               const float* __restrict__ bp,
                                               const float* __restrict__ gp,
                                               float* __restrict__ Etab_g,
                                               float* __restrict__ EcTab_g,
                                               float* __restrict__ Sg,
                                               float* __restrict__ invSg,
                                               int*   __restrict__ endTab_g,
                                               int*   __restrict__ hcolg) {
    __shared__ u64 red[2][8];        // double-buffered wave-partial argmins
    __shared__ float GAll[BB * BB];
    __shared__ float PfxAll[BB * BB];
    __shared__ float ScoldL[BB];
    __shared__ float EtabL[BB * BB];
    __shared__ float EcTabL[BB * BB];
    __shared__ float invSL[BB], SL[BB];
    __shared__ int endL[BB];

    const int tid = threadIdx.x;
    const int lane = tid & 63;
    const int wid = tid >> 6;        // 0..7

    const float beta  = 1.f / (1.f + expf(-bp[0]));
    const float gamma = gp[0];
    const float cuni  = beta / (float)MM;
    const float omb   = 1.f - beta;

    for (int i = tid; i < BB * BB; i += TPB2) {
        GAll[i] = G[i];
        PfxAll[i] = Pfx[i];
    }
    if (tid < BB) { ScoldL[tid] = Scoldg[tid]; endL[tid] = BB; }

    // cold state: 16 columns/thread {c*512 + tid}; prefetch registers ping-pong
    float wu[CPT2], eb0[CPT2], eb1[CPT2];
    #pragma unroll
    for (int c = 0; c < CPT2; ++c) {
        wu[c] = 0.f;
        eb0[c] = Ecold[c * TPB2 + tid];      // row t=0
    }

    // lane-replicated slot state (identical in every wave): slot s == lane, created at step s
    float slot_n2 = 0.f, slot_E = 0.f, slot_ec = 0.f, slot_ecpf = 0.f, wu_hot = 0.f;
    int   slot_j = -1;
    bool  slot_act = false;

    __syncthreads();

    auto step = [&](int t, float (&cur)[CPT2], float (&nxt)[CPT2]) {
        // ---- 1. combine 8 wave-partial argmins -> (j0, minval), per wave via DPP ----
        int j0; float minval;
        if (t == 0) { j0 = 0; minval = 0.f; }
        else {
            u64 pm = red[t & 1][lane & 7];
            pm = wave_min64(pm);
            j0 = (int)(pm & 0xFFFFFFFFu);
            minval = __uint_as_float((unsigned)(pm >> 32));
        }

        // ---- 2. prefetch t+1 (drained by this step's barrier) ----
        if (t + 1 < BB) {
            #pragma unroll
            for (int c = 0; c < CPT2; ++c) nxt[c] = Ecold[(t + 1) * MM + c * TPB2 + tid];
        }
        float latev = 0.f;
        if (lane == t) latev = Ecold[t * MM + j0];

        const float grow_c = GAll[t * BB + lane];    // G[t][lane]
        const float pfx_c  = PfxAll[t * BB + lane];  // Pfx[t][lane]
        const float k2t    = GAll[t * BB + t];       // G[t][t] (uniform)
        const float invk   = __builtin_amdgcn_rsqf(k2t);

        // ---- 3. supersession ballot (before slot t exists) ----
        u64 sup = __ballot(slot_act && (slot_j == j0));
        const bool has_sup = (sup != 0ull);
        const int  ssup = has_sup ? (int)__builtin_ctzll(sup) : 0;

        // ---- 4. hot slot update: pre-zero true e, Delta vs cold, n2 advance ----
        float myDelta = 0.f, e_true = 0.f;
        if (slot_act) {
            float d_ = cuni * pfx_c;                  // lane == lz
            if (lane >= 1) d_ += omb * grow_c;
            e_true = __expf(d_ * invk * __builtin_amdgcn_rsqf(slot_n2));
            myDelta = e_true - slot_ec;
            slot_E = e_true;
            slot_n2 = slot_n2 + 2.f * cuni * d_ + cuni * cuni * k2t;
        }

        // ---- 5. S, invS (identical in every wave) ----
        const float S = ScoldL[t] + wave_sum64(myDelta);
        const float invS = __builtin_amdgcn_rcpf(S);
        const float cuni_t = (t == 0) ? 0.f : cuni;

        // ---- 6. slot w_u update (spike lands on slot t-1 == j0prev) ----
        if (slot_act) {
            float ww = cuni + ((t >= 2 && lane == t - 1) ? omb : 0.f);
            wu_hot = fmaf(gamma, wu_hot, fmaf(e_true, invS, ww));
        }

        // ---- 7. create slot t (fresh from argmin key, or takeover on supersession) ----
        float trans_wu = __int_as_float(__builtin_amdgcn_readlane(__float_as_int(wu_hot), ssup));
        float trans_E  = __int_as_float(__builtin_amdgcn_readlane(__float_as_int(e_true), ssup));
        if (lane == t) {
            slot_j = j0;
            float ww0 = cuni + ((t >= 1) ? omb : 0.f);
            slot_n2 = ww0 * ww0 * k2t;
            slot_act = true;
            slot_ec = latev;
            float fresh_wu = fmaf(gamma, minval, fmaf(latev, invS, cuni_t)); // bit-equal to cold owner's fma
            wu_hot = has_sup ? trans_wu : fresh_wu;
            slot_E = has_sup ? trans_E : latev;
        }
        if (has_sup) {
            if (lane == ssup) slot_act = false;
            if (wid == 0 && lane == t) endL[ssup] = t;
        }
        if (t + 1 < BB && slot_act) slot_ecpf = Ecold[(t + 1) * MM + slot_j];

        // ---- 8. phase C: cold w_u fma + first-index min over 16 cols ----
        float vmin = 0.f; int cbest = 0;
        #pragma unroll
        for (int c = 0; c < CPT2; ++c) {
            float wun = fmaf(gamma, wu[c], fmaf(cur[c], invS, cuni_t));
            wu[c] = wun;
            if (c == 0) { vmin = wun; cbest = 0; }
            else { bool lt = wun < vmin; vmin = lt ? wun : vmin; cbest = lt ? c : cbest; }
        }
        int jmin = cbest * TPB2 + tid;       // ascending c => ascending j => first-index tie-break
        u64 key = (((u64)__float_as_uint(vmin)) << 32) | (unsigned)jmin;

        // owner poisons its cold register for the newly-hot column (future steps via slot)
        if ((j0 & (TPB2 - 1)) == tid) {
            int cj = j0 >> 9;
            #pragma unroll
            for (int c = 0; c < CPT2; ++c) if (c == cj) wu[c] = __builtin_inff();
        }

        // ---- 9. merge slot candidates, DPP wave min, publish wave partial ----
        u64 skey = slot_act ? ((((u64)__float_as_uint(wu_hot)) << 32) | (unsigned)slot_j) : ~0ull;
        key = skey < key ? skey : key;
        key = wave_min64(key);
        if (lane == 0) red[(t + 1) & 1][wid] = key;

        // ---- 10. log step state (wave 0; dumped to global at the end) ----
        if (wid == 0) {
            EtabL[t * BB + lane]  = slot_E;
            EcTabL[t * BB + lane] = slot_ec;
            if (lane == 0) { invSL[t] = invS; SL[t] = S; }
        }

        // ---- 11. advance ----
        if (slot_act) slot_ec = slot_ecpf;
        __syncthreads();                 // the ONE barrier: drains prefetches, publishes red[]
    };

    #pragma unroll 1
    for (int th = 0; th < BB; th += 2) {
        step(th, eb0, eb1);
        step(th + 1, eb1, eb0);
    }

    // epilogue: dump logs
    for (int i = tid; i < BB * BB; i += TPB2) {
        Etab_g[i]  = EtabL[i];
        EcTab_g[i] = EcTabL[i];
    }
    if (tid < BB) {
        Sg[tid] = SL[tid];
        invSg[tid] = invSL[tid];
        endTab_g[tid] = endL[tid];
    }
    if (wid == 0) hcolg[lane] = slot_j;
}

// ---------------- K34: parts GEMM + fused MKhot gather (hcol ready: k2 ran earlier) ----------------
__global__ __launch_bounds__(256) void k34(const float* __restrict__ Ecold, const float* __restrict__ MK0,
                                           const int* __restrict__ hcolg,
                                           float* __restrict__ parts, float* __restrict__ MKhot) {
    __shared__ float Ws[64 * 65];
    __shared__ float Msub[64 * 65];
    const int tid = threadIdx.x;
    const int lane = tid & 63, w = tid >> 6;
    const int d0 = blockIdx.x * 64;
    const int by = blockIdx.y;
    const int t4 = ((w << 2) | (lane >> 4)) << 2;
    const int dq0 = lane & 15;
    int hv = 0;
    if (w == 0) hv = hcolg[lane];          // lane i holds hcol[i]
    float acc[4][4];
    #pragma unroll
    for (int i = 0; i < 4; ++i)
        #pragma unroll
        for (int q = 0; q < 4; ++q) acc[i][q] = 0.f;
    for (int sub = 0; sub < 4; ++sub) {
        int jb = by * 256 + sub * 64;
        #pragma unroll
        for (int i = 0; i < 16; ++i) {
            int e = i * 256 + tid; int r = e >> 6, c = e & 63;
            Ws[r * 65 + c] = Ecold[r * MM + jb + c];
            Msub[r * 65 + c] = MK0[(d0 + r) * MM + jb + c];
        }
        __syncthreads();
        // wave 0: extract any hot columns living in this chunk (each (i, d-tile) written once grid-wide)
        if (w == 0) {
            #pragma unroll 1
            for (int i = 0; i < BB; ++i) {
                int h = __shfl(hv, i) - jb;
                if ((unsigned)h < 64u) MKhot[i * DD + d0 + lane] = Msub[lane * 65 + h];
            }
        }
        #pragma unroll 4
        for (int jl = 0; jl < 64; ++jl) {
            float wv[4], mv[4];
            #pragma unroll
            for (int i = 0; i < 4; ++i) wv[i] = Ws[(t4 + i) * 65 + jl];
            #pragma unroll
            for (int q = 0; q < 4; ++q) mv[q] = Msub[(dq0 + 16 * q) * 65 + jl];
            #pragma unroll
            for (int i = 0; i < 4; ++i)
                #pragma unroll
                for (int q = 0; q < 4; ++q) acc[i][q] += wv[i] * mv[q];
        }
        __syncthreads();
    }
    #pragma unroll
    for (int i = 0; i < 4; ++i)
        #pragma unroll
        for (int q = 0; q < 4; ++q)
            parts[(by * 64 + t4 + i) * DD + d0 + dq0 + 16 * q] = acc[i][q];
}

// ---------------- K4: rebuild A/Dcol rows + final combine ----------------
__global__ __launch_bounds__(512) void k4_final(const float* __restrict__ parts,
                                                const float* __restrict__ K,
                                                const float* __restrict__ Etab,
                                                const float* __restrict__ EcTab,
                                                const int*   __restrict__ endTab,
                                                const float* __restrict__ Sg,
                                                const float* __restrict__ invSg,
                                                const float* __restrict__ MKhot,
                                                const float* __restrict__ bp,
                                                float* __restrict__ out) {
    __shared__ float Arow[BB];
    __shared__ float Drow[BB];
    int t = blockIdx.x, d = threadIdx.x;
    if (d < BB) {
        const float beta = 1.f / (1.f + expf(-bp[0]));
        const float cuni = beta / (float)MM;
        const float omb  = 1.f - beta;
        int s = d;
        float Ev = Etab[t * BB + s];
        int endv = endTab[s];
        bool act = (s <= t) && (t < endv);
        float S = Sg[t], invS = invSg[t];
        float ev = act ? Ev : 0.f;
        float x = ev;
        #pragma unroll
        for (int o = 1; o < 64; o <<= 1) {
            float y = __shfl_down(x, o);
            if (s + o < 64) x += y;
        }
        float suf = x - ev;
        float arow = 0.f;
        if (s < t) {
            float Qe = S - suf;
            arow = cuni * Qe;
            if (s >= 1 && act) arow += omb * Ev;
            arow *= invS;
        }
        Arow[s] = arow;
        Drow[s] = act ? (-invS * EcTab[t * BB + s]) : 0.f;
    }
    __syncthreads();
    float isv = invSg[t];
    float s1 = 0.f;
    #pragma unroll
    for (int p = 0; p < 32; ++p) s1 += parts[(p * 64 + t) * DD + d];
    float s2 = 0.f;
    for (int i = 0; i < BB; ++i) s2 += Drow[i] * MKhot[i * DD + d];
    float s3 = 0.f;
    for (int i = 0; i < BB; ++i) s3 += Arow[i] * K[i * DD + d];
    out[t * DD + d] = isv * s1 + s2 + s3;
}

extern "C" void kernel_launch(void* const* d_in, const int* in_sizes, int n_in,
                              void* d_out, int out_size, void* d_ws, size_t ws_size,
                              hipStream_t stream) {
    const float* K   = (const float*)d_in[0];   // k: [B,1,D]
    // d_in[1] = u: unused (MU never read for the output)
    const float* MK0 = (const float*)d_in[2];   // memory_knowledge: [D,M]
    // d_in[3] = memory_understanding: unused
    const float* bp  = (const float*)d_in[4];   // beta_param
    const float* gp  = (const float*)d_in[5];   // memory_gamma

    float* ws    = (float*)d_ws;
    float* G     = ws;                  // 4096
    float* Pfx   = G + 4096;            // 4096
    float* S0p   = Pfx + 4096;          // 2*64*8192 = 1048576
    float* n2p   = S0p + 1048576;       // 16384
    float* Ecold = n2p + 16384;         // 524288
    float* Scold = Ecold + 524288;      // 64
    float* Etab  = Scold + 64;          // 4096
    float* EcTab = Etab + 4096;         // 4096
    float* Sarr  = EcTab + 4096;        // 64
    float* invS  = Sarr + 64;           // 64
    float* MKhot = invS + 64;           // 32768
    float* parts = MKhot + 32768;       // 32*64*512 = 1048576
    int*   hcol  = (int*)(parts + 1048576);  // 64
    int*   endT  = hcol + 64;                // 64
    float* out   = (float*)d_out;       // [B,1,D] f32

    k01       <<<257, 256, 0, stream>>>(K, MK0, S0p, n2p, G, Pfx);
    k1b_ecold <<<32, 256, 0, stream>>>(S0p, G, Pfx, n2p, bp, Ecold);
    ks_rowsum <<<64, 256, 0, stream>>>(Ecold, Scold);
    k2_scan   <<<1, TPB2, 0, stream>>>(Ecold, G, Pfx, Scold, bp, gp,
                                       Etab, EcTab, Sarr, invS, endT, hcol);
    k34       <<<dim3(8, 32), 256, 0, stream>>>(Ecold, MK0, hcol, parts, MKhot);
    k4_final  <<<64, 512, 0, stream>>>(parts, K, Etab, EcTab, endT, Sarr, invS, MKhot, bp, out);
}

// Round 9
// 312.852 us; speedup vs baseline: 1.2447x; 1.2447x over previous
//
#include <hip/hip_runtime.h>
#include <math.h>

#define BB 64
#define DD 512
#define MM 8192
#define TPB 1024
#define CPT 8   // MM / TPB cold columns per thread (scan role)

typedef unsigned long long u64;

// ---------------- DPP wave-64 primitives ----------------
template<int CTRL>
__device__ __forceinline__ float dpp_addf(float x) {
    int y = __builtin_amdgcn_update_dpp(0, __float_as_int(x), CTRL, 0xF, 0xF, true);
    return x + __int_as_float(y);
}
__device__ __forceinline__ float wave_sum64(float x) {
    x = dpp_addf<0x111>(x); x = dpp_addf<0x112>(x); x = dpp_addf<0x114>(x); x = dpp_addf<0x118>(x);
    x = dpp_addf<0x142>(x); x = dpp_addf<0x143>(x);
    return __int_as_float(__builtin_amdgcn_readlane(__float_as_int(x), 63));
}
template<int CTRL>
__device__ __forceinline__ u64 dpp_min_step(u64 k) {
    unsigned lo = (unsigned)k, hi = (unsigned)(k >> 32);
    unsigned nlo = (unsigned)__builtin_amdgcn_update_dpp((int)0xFFFFFFFFu, (int)lo, CTRL, 0xF, 0xF, false);
    unsigned nhi = (unsigned)__builtin_amdgcn_update_dpp((int)0xFFFFFFFFu, (int)hi, CTRL, 0xF, 0xF, false);
    u64 nk = (((u64)nhi) << 32) | (u64)nlo;
    return nk < k ? nk : k;
}
__device__ __forceinline__ u64 wave_min64(u64 k) {
    k = dpp_min_step<0x111>(k); k = dpp_min_step<0x112>(k); k = dpp_min_step<0x114>(k);
    k = dpp_min_step<0x118>(k); k = dpp_min_step<0x142>(k); k = dpp_min_step<0x143>(k);
    unsigned lo = (unsigned)__builtin_amdgcn_readlane((int)(unsigned)k, 63);
    unsigned hi = (unsigned)__builtin_amdgcn_readlane((int)(unsigned)(k >> 32), 63);
    return (((u64)hi) << 32) | (u64)lo;
}
__device__ __forceinline__ float readlane_f(float v, int l) {
    return __int_as_float(__builtin_amdgcn_readlane(__float_as_int(v), l));
}

// ---------------- K01: blocks 0..255 = k1 (S0p, n2p); block 256 = k0 (G, Pfx) + flag zero ----------------
__global__ __launch_bounds__(256) void k01(const float* __restrict__ K, const float* __restrict__ MK0,
                                           float* __restrict__ S0p, float* __restrict__ n2p,
                                           float* __restrict__ G, float* __restrict__ Pfx,
                                           int* __restrict__ flagp) {
    __shared__ float lds[12352];
    const int tid = threadIdx.x;
    const int lane = tid & 63, w = tid >> 6;

    if (blockIdx.x == 256) {
        if (tid == 0) flagp[0] = 0;        // zero the ks->scan flag (ws is 0xAA-poisoned)
        // ---------------- k0 ----------------
        float* Ks = lds;                   // [64][129]
        float* Gs = lds + 64 * 129;        // [64][64]
        const int s = lane;
        const int rq = w;
        float acc[16];
        #pragma unroll
        for (int i = 0; i < 16; ++i) acc[i] = 0.f;
        for (int d0 = 0; d0 < DD; d0 += 128) {
            #pragma unroll
            for (int i = 0; i < 32; ++i) {
                int e = i * 256 + tid; int r = e >> 7, c = e & 127;
                Ks[r * 129 + c] = K[r * DD + d0 + c];
            }
            __syncthreads();
            for (int dl = 0; dl < 128; ++dl) {
                float kv = Ks[s * 129 + dl];
                #pragma unroll
                for (int i = 0; i < 16; ++i) acc[i] += Ks[(rq * 16 + i) * 129 + dl] * kv;
            }
            __syncthreads();
        }
        #pragma unroll
        for (int i = 0; i < 16; ++i) {
            G[(rq * 16 + i) * BB + s] = acc[i];
            Gs[(rq * 16 + i) * BB + s] = acc[i];
        }
        __syncthreads();
        #pragma unroll 1
        for (int r = 0; r < 16; ++r) {
            int row = rq * 16 + r;
            float x = (s < row) ? Gs[row * BB + s] : 0.f;
            #pragma unroll
            for (int o = 1; o < 64; o <<= 1) {
                float y = __shfl_down(x, o);
                if (s + o < 64) x += y;
            }
            Pfx[row * BB + s] = x;
        }
        return;
    }

    // ---------------- k1 ----------------
    float* Ks = lds;
    float* Ms = lds + 4160;
    float* sq = lds + 8320;
    const int bx = blockIdx.x;
    const int jb = (bx & 127) * 64;
    const int dbase = (bx >> 7) * 256;
    const int t4 = ((w << 2) | (lane >> 4)) << 2;
    const int jq0 = lane & 15;
    float acc[4][4];
    #pragma unroll
    for (int i = 0; i < 4; ++i)
        #pragma unroll
        for (int q = 0; q < 4; ++q) acc[i][q] = 0.f;
    float sqa = 0.f;
    for (int dt = 0; dt < 4; ++dt) {
        int d0 = dbase + dt * 64;
        #pragma unroll
        for (int i = 0; i < 16; ++i) {
            int e = i * 256 + tid; int r = e >> 6, c = e & 63;
            Ks[r * 65 + c] = K[r * DD + d0 + c];
            float m = MK0[(d0 + r) * MM + jb + c];
            Ms[r * 65 + c] = m;
            sqa += m * m;
        }
        __syncthreads();
        #pragma unroll 4
        for (int dl = 0; dl < 64; ++dl) {
            float kv[4], mv[4];
            #pragma unroll
            for (int i = 0; i < 4; ++i) kv[i] = Ks[(t4 + i) * 65 + dl];
            #pragma unroll
            for (int q = 0; q < 4; ++q) mv[q] = Ms[dl * 65 + jq0 + 16 * q];
            #pragma unroll
            for (int i = 0; i < 4; ++i)
                #pragma unroll
                for (int q = 0; q < 4; ++q) acc[i][q] += kv[i] * mv[q];
        }
        __syncthreads();
    }
    #pragma unroll
    for (int i = 0; i < 4; ++i)
        #pragma unroll
        for (int q = 0; q < 4; ++q)
            S0p[(bx >> 7) * BB * MM + (t4 + i) * MM + jb + jq0 + 16 * q] = acc[i][q];
    sq[w * 64 + lane] = sqa;
    __syncthreads();
    if (w == 0) n2p[(bx >> 7) * MM + jb + lane] =
        sq[lane] + sq[64 + lane] + sq[128 + lane] + sq[192 + lane];
}

// ---------------- K1b: cold-hypothesis E matrix ----------------
__global__ __launch_bounds__(256) void k1b_ecold(const float* __restrict__ S0p,
                                                 const float* __restrict__ G,
                                                 const float* __restrict__ Pfx,
                                                 const float* __restrict__ n2p,
                                                 const float* __restrict__ bp,
                                                 float* __restrict__ Ecold) {
    __shared__ float Pfx0s[BB], invks[BB], k2s[BB];
    int tid = threadIdx.x;
    int j = blockIdx.x * 256 + tid;
    if (tid < BB) {
        float g = G[tid * BB + tid];
        k2s[tid] = g;
        invks[tid] = __builtin_amdgcn_rsqf(g);
        Pfx0s[tid] = Pfx[tid * BB + 0];
    }
    const float beta = 1.f / (1.f + expf(-bp[0]));
    const float cuni = beta / (float)MM;
    float n2c = n2p[j] + n2p[MM + j];
    __syncthreads();
    for (int t = 0; t < BB; ++t) {
        float s0 = S0p[t * MM + j] + S0p[(BB + t) * MM + j];
        float d_ = s0 + cuni * Pfx0s[t];
        float cosv = d_ * invks[t] * __builtin_amdgcn_rsqf(n2c);
        float ee = __expf(cosv);
        Ecold[t * MM + j] = ee;
        n2c = n2c + 2.f * cuni * d_ + cuni * cuni * k2s[t];
    }
}

// ---------------- MEGA: blocks 0..63 = ks (Scold + flag); block 64 = scan (R7-exact);
//                  blocks 65..320 = k3 parts GEMM (no dependency on the scan) ----------------
__global__ __launch_bounds__(1024) void mega(const float* __restrict__ Ecold,
                                             const float* __restrict__ G,
                                             const float* __restrict__ Pfx,
                                             float* __restrict__ Scoldg,
                                             const float* __restrict__ bp,
                                             const float* __restrict__ gp,
                                             const float* __restrict__ MK0,
                                             int* __restrict__ flagp,
                                             float* __restrict__ Etab_g,
                                             float* __restrict__ EcTab_g,
                                             float* __restrict__ Sg,
                                             float* __restrict__ invSg,
                                             int*   __restrict__ endTab_g,
                                             int*   __restrict__ hcolg,
                                             float* __restrict__ parts) {
    __shared__ __align__(16) char smem[34048];
    const int tid = threadIdx.x;
    const int lane = tid & 63;
    const int wid = tid >> 6;

    if (blockIdx.x < 64) {
        // ---------------- ks role: Scold[t], R7-bit-exact (256 active threads) ----------------
        float* sw = (float*)smem;
        const int t = blockIdx.x;
        if (tid < 256) {
            float s = 0.f;
            #pragma unroll
            for (int i = 0; i < 32; ++i) s += Ecold[t * MM + i * 256 + tid];
            #pragma unroll
            for (int o = 32; o > 0; o >>= 1) s += __shfl_down(s, o);
            if (lane == 0) sw[wid] = s;
        }
        __syncthreads();
        if (tid == 0) {
            Scoldg[t] = sw[0] + sw[1] + sw[2] + sw[3];
            __threadfence();
            atomicAdd(flagp, 1);
        }
        return;
    }

    if (blockIdx.x > 64) {
        // ---------------- k3 role: parts[(by*64+t)*DD + d0 + d] = sum_j Ecold[t,j]*MK0[d,j] ----------------
        float* Ws   = (float*)smem;            // [64][65] (t x j)
        float* Msub = Ws + 64 * 65;            // [64][65] (d x j)
        const int b = blockIdx.x - 65;         // 0..255
        const int d0 = (b & 7) * 64;
        const int by = b >> 3;                 // 0..31
        const int t4 = wid * 4;                // wave owns 4 t-rows; lane = d-col
        float acc[4] = {0.f, 0.f, 0.f, 0.f};
        for (int sub = 0; sub < 4; ++sub) {
            int jb = by * 256 + sub * 64;
            #pragma unroll
            for (int i = 0; i < 4; ++i) {
                int e = i * 1024 + tid; int r = e >> 6, c = e & 63;
                Ws[r * 65 + c] = Ecold[r * MM + jb + c];
                Msub[r * 65 + c] = MK0[(d0 + r) * MM + jb + c];
            }
            __syncthreads();
            #pragma unroll 4
            for (int jl = 0; jl < 64; ++jl) {
                float mv = Msub[lane * 65 + jl];
                #pragma unroll
                for (int i = 0; i < 4; ++i) acc[i] += Ws[(t4 + i) * 65 + jl] * mv;
            }
            __syncthreads();
        }
        #pragma unroll
        for (int i = 0; i < 4; ++i)
            parts[(by * 64 + t4 + i) * DD + d0 + lane] = acc[i];
        return;
    }

    // ---------------- scan role: R7 k2_scan verbatim (16 waves, 8 cols/thread) ----------------
    u64*   red    = (u64*)smem;                    // [2][16]
    float* EtabL  = (float*)(smem + 256);          // 4096
    float* EcTabL = (float*)(smem + 256 + 16384);  // 4096
    float* invSL  = (float*)(smem + 33024);        // 64
    float* SL     = (float*)(smem + 33280);        // 64
    int*   endL   = (int*)(smem + 33536);          // 64

    const float beta  = 1.f / (1.f + expf(-bp[0]));
    const float gamma = gp[0];
    const float cuni  = beta / (float)MM;
    const float omb   = 1.f - beta;

    if (tid < BB) endL[tid] = BB;

    // wait for ks blocks to publish Scold (release/acquire via flag)
    if (tid == 0) { while (atomicAdd(flagp, 0) < 64) {} }
    __syncthreads();
    __threadfence();

    float wu[CPT], eb0[CPT], eb1[CPT];
    #pragma unroll
    for (int c = 0; c < CPT; ++c) {
        wu[c] = 0.f;
        eb0[c] = Ecold[c * TPB + tid];       // row t=0
    }

    float slot_n2 = 0.f, slot_E = 0.f, slot_ec = 0.f, slot_ecpf = 0.f, wu_hot = 0.f;
    int   slot_j = -1;
    bool  slot_act = false;

    float grow_c = G[lane], pfx_c = Pfx[lane];   // row t=0
    float Ssc_c = Scoldg[0];
    __syncthreads();

    auto step = [&](int t, float (&cur)[CPT], float (&nxt)[CPT]) {
        int j0; float minval;
        if (t == 0) { j0 = 0; minval = 0.f; }
        else {
            u64 pm = red[(t & 1) * 16 + (lane & 15)];
            pm = wave_min64(pm);
            j0 = (int)(pm & 0xFFFFFFFFu);
            minval = __uint_as_float((unsigned)(pm >> 32));
        }

        if (t + 1 < BB) {
            #pragma unroll
            for (int c = 0; c < CPT; ++c) nxt[c] = Ecold[(t + 1) * MM + c * TPB + tid];
        }
        float grow_n = (t + 1 < BB) ? G[(t + 1) * BB + lane] : 0.f;
        float pfx_n  = (t + 1 < BB) ? Pfx[(t + 1) * BB + lane] : 0.f;
        float Ssc_n  = (t + 1 < BB) ? Scoldg[t + 1] : 0.f;
        float latev = 0.f;
        if (lane == t) latev = Ecold[t * MM + j0];

        const float k2t  = readlane_f(grow_c, t);
        const float invk = __builtin_amdgcn_rsqf(k2t);

        u64 sup = __ballot(slot_act && (slot_j == j0));
        const bool has_sup = (sup != 0ull);
        const int  ssup = has_sup ? (int)__builtin_ctzll(sup) : 0;

        float myDelta = 0.f, e_true = 0.f;
        if (slot_act) {
            float d_ = cuni * pfx_c;
            if (lane >= 1) d_ += omb * grow_c;
            e_true = __expf(d_ * invk * __builtin_amdgcn_rsqf(slot_n2));
            myDelta = e_true - slot_ec;
            slot_E = e_true;
            slot_n2 = slot_n2 + 2.f * cuni * d_ + cuni * cuni * k2t;
        }

        const float S = Ssc_c + wave_sum64(myDelta);
        const float invS = __builtin_amdgcn_rcpf(S);
        const float cuni_t = (t == 0) ? 0.f : cuni;

        if (slot_act) {
            float ww = cuni + ((t >= 2 && lane == t - 1) ? omb : 0.f);
            wu_hot = fmaf(gamma, wu_hot, fmaf(e_true, invS, ww));
        }

        float trans_wu = readlane_f(wu_hot, ssup);
        float trans_E  = readlane_f(e_true, ssup);
        if (lane == t) {
            slot_j = j0;
            float ww0 = cuni + ((t >= 1) ? omb : 0.f);
            slot_n2 = ww0 * ww0 * k2t;
            slot_act = true;
            slot_ec = latev;
            float fresh_wu = fmaf(gamma, minval, fmaf(latev, invS, cuni_t));
            wu_hot = has_sup ? trans_wu : fresh_wu;
            slot_E = has_sup ? trans_E : latev;
        }
        if (has_sup) {
            if (lane == ssup) slot_act = false;
            if (wid == 0 && lane == t) endL[ssup] = t;
        }
        if (t + 1 < BB && slot_act) slot_ecpf = Ecold[(t + 1) * MM + slot_j];

        float vmin = 0.f; int jmin = 0;
        #pragma unroll
        for (int c = 0; c < CPT; ++c) {
            float wun = fmaf(gamma, wu[c], fmaf(cur[c], invS, cuni_t));
            wu[c] = wun;
            int j = c * TPB + tid;
            if (c == 0) { vmin = wun; jmin = j; }
            else if (wun < vmin) { vmin = wun; jmin = j; }
        }
        u64 key = (((u64)__float_as_uint(vmin)) << 32) | (unsigned)jmin;

        if ((j0 & (TPB - 1)) == tid) {
            int cj = j0 >> 10;
            #pragma unroll
            for (int c = 0; c < CPT; ++c) if (c == cj) wu[c] = __builtin_inff();
        }

        u64 skey = slot_act ? ((((u64)__float_as_uint(wu_hot)) << 32) | (unsigned)slot_j) : ~0ull;
        key = skey < key ? skey : key;
        key = wave_min64(key);
        if (lane == 0) red[((t + 1) & 1) * 16 + wid] = key;

        if (wid == 0) {
            EtabL[t * BB + lane]  = slot_E;
            EcTabL[t * BB + lane] = slot_ec;
            if (lane == 0) { invSL[t] = invS; SL[t] = S; }
        }

        if (slot_act) slot_ec = slot_ecpf;
        grow_c = grow_n; pfx_c = pfx_n; Ssc_c = Ssc_n;
        __syncthreads();
    };

    #pragma unroll 1
    for (int th = 0; th < BB; th += 2) {
        step(th, eb0, eb1);
        step(th + 1, eb1, eb0);
    }

    for (int i = tid; i < BB * BB; i += TPB) {
        Etab_g[i]  = EtabL[i];
        EcTab_g[i] = EcTabL[i];
    }
    if (tid < BB) {
        Sg[tid] = SL[tid];
        invSg[tid] = invSL[tid];
        endTab_g[tid] = endL[tid];
    }
    if (wid == 0) hcolg[lane] = slot_j;
}

// ---------------- K4: rebuild A/Dcol rows + final combine (s2 gathers MK0 columns directly) ----------------
__global__ __launch_bounds__(512) void k4_final(const float* __restrict__ parts,
                                                const float* __restrict__ K,
                                                const float* __restrict__ MK0,
                                                const float* __restrict__ Etab,
                                                const float* __restrict__ EcTab,
                                                const int*   __restrict__ endTab,
                                                const float* __restrict__ Sg,
                                                const float* __restrict__ invSg,
                                                const int*   __restrict__ hcolg,
                                                const float* __restrict__ bp,
                                                float* __restrict__ out) {
    __shared__ float Arow[BB];
    __shared__ float Drow[BB];
    __shared__ int   hcolL[BB];
    int t = blockIdx.x, d = threadIdx.x;
    if (d < BB) {
        hcolL[d] = hcolg[d];
        const float beta = 1.f / (1.f + expf(-bp[0]));
        const float cuni = beta / (float)MM;
        const float omb  = 1.f - beta;
        int s = d;
        float Ev = Etab[t * BB + s];
        int endv = endTab[s];
        bool act = (s <= t) && (t < endv);
        float S = Sg[t], invS = invSg[t];
        float ev = act ? Ev : 0.f;
        float x = ev;
        #pragma unroll
        for (int o = 1; o < 64; o <<= 1) {
            float y = __shfl_down(x, o);
            if (s + o < 64) x += y;
        }
        float suf = x - ev;
        float arow = 0.f;
        if (s < t) {
            float Qe = S - suf;
            arow = cuni * Qe;
            if (s >= 1 && act) arow += omb * Ev;
            arow *= invS;
        }
        Arow[s] = arow;
        Drow[s] = act ? (-invS * EcTab[t * BB + s]) : 0.f;
    }
    __syncthreads();
    float isv = invSg[t];
    float s1 = 0.f;
    #pragma unroll
    for (int p = 0; p < 32; ++p) s1 += parts[(p * 64 + t) * DD + d];
    float s2 = 0.f;
    for (int i = 0; i < BB; ++i) s2 += Drow[i] * MK0[d * MM + hcolL[i]];
    float s3 = 0.f;
    for (int i = 0; i < BB; ++i) s3 += Arow[i] * K[i * DD + d];
    out[t * DD + d] = isv * s1 + s2 + s3;
}

extern "C" void kernel_launch(void* const* d_in, const int* in_sizes, int n_in,
                              void* d_out, int out_size, void* d_ws, size_t ws_size,
                              hipStream_t stream) {
    const float* K   = (const float*)d_in[0];   // k: [B,1,D]
    // d_in[1] = u: unused (MU never read for the output)
    const float* MK0 = (const float*)d_in[2];   // memory_knowledge: [D,M]
    // d_in[3] = memory_understanding: unused
    const float* bp  = (const float*)d_in[4];   // beta_param
    const float* gp  = (const float*)d_in[5];   // memory_gamma

    float* ws    = (float*)d_ws;
    float* G     = ws;                  // 4096
    float* Pfx   = G + 4096;            // 4096
    float* S0p   = Pfx + 4096;          // 2*64*8192 = 1048576
    float* n2p   = S0p + 1048576;       // 16384
    float* Ecold = n2p + 16384;         // 524288
    float* Scold = Ecold + 524288;      // 64
    float* Etab  = Scold + 64;          // 4096
    float* EcTab = Etab + 4096;         // 4096
    float* Sarr  = EcTab + 4096;        // 64
    float* invS  = Sarr + 64;           // 64
    float* parts = invS + 64;           // 32*64*512 = 1048576
    int*   hcol  = (int*)(parts + 1048576);  // 64
    int*   endT  = hcol + 64;                // 64
    int*   flag  = endT + 64;                // 1
    float* out   = (float*)d_out;       // [B,1,D] f32

    k01       <<<257, 256, 0, stream>>>(K, MK0, S0p, n2p, G, Pfx, flag);
    k1b_ecold <<<32, 256, 0, stream>>>(S0p, G, Pfx, n2p, bp, Ecold);
    mega      <<<321, 1024, 0, stream>>>(Ecold, G, Pfx, Scold, bp, gp, MK0, flag,
                                         Etab, EcTab, Sarr, invS, endT, hcol, parts);
    k4_final  <<<64, 512, 0, stream>>>(parts, K, MK0, Etab, EcTab, endT, Sarr, invS, hcol, bp, out);
}